// Round 1
// 75.357 us; speedup vs baseline: 1.0849x; 1.0849x over previous
//
#include <hip/hip_runtime.h>

#define DIM 1024
#define NQ 10

// ---------- complex helpers (float2 = {re, im}) ----------
__device__ __forceinline__ float2 cmul(float2 a, float2 b) {
    return make_float2(a.x * b.x - a.y * b.y, a.x * b.y + a.y * b.x);
}
__device__ __forceinline__ float2 cadd(float2 a, float2 b) {
    return make_float2(a.x + b.x, a.y + b.y);
}
__device__ __forceinline__ float2 csub(float2 a, float2 b) {
    return make_float2(a.x - b.x, a.y - b.y);
}
__device__ __forceinline__ float2 cconj(float2 a) { return make_float2(a.x, -a.y); }

__device__ __forceinline__ void mm2(const float2* A, const float2* B, float2* C) {
    C[0] = cadd(cmul(A[0], B[0]), cmul(A[1], B[2]));
    C[1] = cadd(cmul(A[0], B[1]), cmul(A[1], B[3]));
    C[2] = cadd(cmul(A[2], B[0]), cmul(A[3], B[2]));
    C[3] = cadd(cmul(A[2], B[1]), cmul(A[3], B[3]));
}

// G[q*4..] = Rz(+w)·Ry(+w)·Rx(+w) (K1 factor). Msh[q*4..] = u2† Z u2 (q<6, sign=-1)
__device__ __forceinline__ void compute_gates(const float* __restrict__ weight,
                                              float2* G, float2* Msh, int tid) {
    if (tid < NQ) {
        int q = tid;
        const float WM = 0.632455532033676f;  // sqrt(2/5)
        float px = weight[q]      * WM * 0.5f;
        float py = weight[q + 10] * WM * 0.5f;
        float pz = weight[q + 20] * WM * 0.5f;
        float cx = cosf(px), sx = sinf(px);
        float cy = cosf(py), sy = sinf(py);
        float cz = cosf(pz), sz = sinf(pz);
        {
            float2 Rx[4] = { {cx, 0.f}, {0.f, -sx}, {0.f, -sx}, {cx, 0.f} };
            float2 Ry[4] = { {cy, 0.f}, {-sy, 0.f}, {sy, 0.f}, {cy, 0.f} };
            float2 Rz[4] = { {cz, -sz}, {0.f, 0.f}, {0.f, 0.f}, {cz, sz} };
            float2 T[4], u[4];
            mm2(Ry, Rx, T);
            mm2(Rz, T, u);
            G[q * 4 + 0] = u[0]; G[q * 4 + 1] = u[1];
            G[q * 4 + 2] = u[2]; G[q * 4 + 3] = u[3];
        }
        if (Msh && q < 6) {
            float nsx = -sx, nsy = -sy, nsz = -sz;
            float2 Rx[4] = { {cx, 0.f}, {0.f, -nsx}, {0.f, -nsx}, {cx, 0.f} };
            float2 Ry[4] = { {cy, 0.f}, {-nsy, 0.f}, {nsy, 0.f}, {cy, 0.f} };
            float2 Rz[4] = { {cz, -nsz}, {0.f, 0.f}, {0.f, 0.f}, {cz, nsz} };
            float2 T[4], u2[4];
            mm2(Ry, Rx, T);
            mm2(Rz, T, u2);
            for (int i = 0; i < 2; i++)
                for (int j = 0; j < 2; j++) {
                    float2 v = csub(cmul(cconj(u2[0 * 2 + i]), u2[0 * 2 + j]),
                                    cmul(cconj(u2[1 * 2 + i]), u2[1 * 2 + j]));
                    Msh[q * 4 + i * 2 + j] = v;
                }
        }
    }
}

// ---------- pass 1: z = x · K1†, stored TRANSPOSED as zt[c][r] ----------
// 256 blocks x 512 threads (8 waves -> 2 waves/SIMD). Block = 4 rows; wave pair
// per row: h = c bit 9. Wave element c = h<<9 | j<<6 | lane (j = 0..7).
// Stages q=1..3 on j bits (registers), q=4..9 on lane bits (shfl).
// Stage q=0 (c bit 9) is fused into the LDS-transpose store phase for free.
__global__ __launch_bounds__(512) void pass1(const float* __restrict__ x,
                                             const float* __restrict__ weight,
                                             float2* __restrict__ zt,
                                             float* __restrict__ out) {
    __shared__ float2 G[40];
    __shared__ float2 sh[DIM * 5];  // transpose tile sh[c*5 + r_loc]; pitch 5 -> 4-way max bank alias
    int tid = threadIdx.x;
    int lane = tid & 63;
    int w = tid >> 6;       // wave 0..7
    int rl = w >> 1;        // row-in-block 0..3
    int h = w & 1;          // c bit 9
    int r = blockIdx.x * 4 + rl;

    // coalesced scalar loads: per j, 64 lanes read 256 contiguous bytes
    const float* xp = x + r * DIM + (h << 9) + lane;
    float2 v[8];
#pragma unroll
    for (int j = 0; j < 8; j++) v[j] = make_float2(xp[j * 64], 0.f);

    compute_gates(weight, G, nullptr, tid);
    if (blockIdx.x == 0 && tid == 0) out[0] = 0.f;  // pass2's atomics start after pass1 retires
    __syncthreads();

    // register stages q=1..3 (c bits 8..6 = j bits 2..0), conj gates
#pragma unroll
    for (int q = 1; q < 4; q++) {
        float2 u0 = cconj(G[q * 4]),     u1 = cconj(G[q * 4 + 1]);
        float2 u2 = cconj(G[q * 4 + 2]), u3 = cconj(G[q * 4 + 3]);
        const int hb = 1 << (3 - q);  // 4,2,1
#pragma unroll
        for (int j0 = 0; j0 < 8; j0++) {
            if ((j0 & hb) == 0) {
                int j1 = j0 | hb;
                float2 s0 = v[j0], s1 = v[j1];
                v[j0] = cadd(cmul(u0, s0), cmul(u1, s1));
                v[j1] = cadd(cmul(u2, s0), cmul(u3, s1));
            }
        }
    }
    // shfl stages q=4..9 (c bits 5..0 = lane bits 5..0)
#pragma unroll
    for (int q = 4; q < 10; q++) {
        float2 u0 = cconj(G[q * 4]),     u1 = cconj(G[q * 4 + 1]);
        float2 u2 = cconj(G[q * 4 + 2]), u3 = cconj(G[q * 4 + 3]);
        const int X = 1 << (9 - q);
        bool up = (lane & X) != 0;
        float2 go = up ? u3 : u0;
        float2 gp = up ? u2 : u1;
#pragma unroll
        for (int j = 0; j < 8; j++) {
            float2 p;
            p.x = __shfl_xor(v[j].x, X, 64);
            p.y = __shfl_xor(v[j].y, X, 64);
            v[j] = cadd(cmul(go, v[j]), cmul(gp, p));
        }
    }
    // write transpose tile
#pragma unroll
    for (int j = 0; j < 8; j++) {
        int c = (h << 9) | (j << 6) | lane;
        sh[c * 5 + rl] = v[j];
    }
    __syncthreads();
    // fused q=0 (c bit 9) + transposed store: thread owns columns cL=tid, cH=tid+512,
    // which are exactly each other's q=0 partners -> LDS reads shared.
    {
        float2 g00 = cconj(G[0]), g01 = cconj(G[1]), g10 = cconj(G[2]), g11 = cconj(G[3]);
        int cL = tid, cH = tid + 512;
        int r0 = blockIdx.x * 4;
        float2 oL[4], oH[4];
#pragma unroll
        for (int k = 0; k < 4; k++) {
            float2 L = sh[cL * 5 + k];
            float2 H = sh[cH * 5 + k];
            oL[k] = cadd(cmul(g00, L), cmul(g01, H));
            oH[k] = cadd(cmul(g10, L), cmul(g11, H));
        }
        float4* pL = (float4*)(zt + cL * DIM + r0);
        float4* pH = (float4*)(zt + cH * DIM + r0);
        pL[0] = make_float4(oL[0].x, oL[0].y, oL[1].x, oL[1].y);
        pL[1] = make_float4(oL[2].x, oL[2].y, oL[3].x, oL[3].y);
        pH[0] = make_float4(oH[0].x, oH[0].y, oH[1].x, oH[1].y);
        pH[1] = make_float4(oH[2].x, oH[2].y, oH[3].x, oH[3].y);
    }
}

// ---------- pass 2: w = K1·z (unit-stride loads from zt) + closed-form extract ----------
// 256 blocks x 512 threads; block = 4 columns, wave pair per column (h = r bit 9).
// Wave element r = h<<9 | lane<<3 | j. q=0 fused into load (reads both halves);
// q=1..6 shfl on lane bits, q=7..9 register on j bits.
// Extraction: pi(r)&15==pi(c)&15 forces h^parity(lane)==t3 with wave-uniform j_sel,
// and b05 bits are prefix-parities of lane -> per-lane M6, no shuffles needed.
__global__ __launch_bounds__(512) void pass2(const float2* __restrict__ zt,
                                             const float* __restrict__ weight,
                                             float* __restrict__ out) {
    __shared__ float2 G[40];
    __shared__ float2 Msh[24];
    __shared__ float part[8];
    int tid = threadIdx.x;
    int lane = tid & 63;
    int w = tid >> 6;
    int pr = w >> 1;    // column-in-block 0..3
    int h = w & 1;      // r bit 9
    int c = blockIdx.x * 4 + pr;

    // contiguous 64 B per lane, 4 KB per wave per half: perfect coalescing
    const float4* zp = (const float4*)(zt + c * DIM);
    const float4* po = zp + h * 256 + lane * 4;          // own half (r bit9 = h)
    const float4* pp = zp + (1 - h) * 256 + lane * 4;    // partner half
    float2 a[8], b[8];
#pragma unroll
    for (int k = 0; k < 4; k++) {
        float4 t0 = po[k];
        a[2 * k]     = make_float2(t0.x, t0.y);
        a[2 * k + 1] = make_float2(t0.z, t0.w);
        float4 t1 = pp[k];
        b[2 * k]     = make_float2(t1.x, t1.y);
        b[2 * k + 1] = make_float2(t1.z, t1.w);
    }
    compute_gates(weight, G, Msh, tid);
    __syncthreads();

    // q=0 (r bit 9) fused at load: new = G[h][h]*own + G[h][1-h]*partner
    float2 v[8];
    {
        float2 ga = h ? G[3] : G[0];
        float2 gb = h ? G[2] : G[1];
#pragma unroll
        for (int j = 0; j < 8; j++) v[j] = cadd(cmul(ga, a[j]), cmul(gb, b[j]));
    }
    // shfl stages q=1..6 (r bits 8..3 = lane bits 5..0)
#pragma unroll
    for (int q = 1; q < 7; q++) {
        float2 u0 = G[q * 4], u1 = G[q * 4 + 1], u2 = G[q * 4 + 2], u3 = G[q * 4 + 3];
        const int X = 1 << (6 - q);
        bool up = (lane & X) != 0;
        float2 go = up ? u3 : u0;
        float2 gp = up ? u2 : u1;
#pragma unroll
        for (int j = 0; j < 8; j++) {
            float2 p;
            p.x = __shfl_xor(v[j].x, X, 64);
            p.y = __shfl_xor(v[j].y, X, 64);
            v[j] = cadd(cmul(go, v[j]), cmul(gp, p));
        }
    }
    // register stages q=7..9 (r bits 2..0 = j bits 2..0)
#pragma unroll
    for (int q = 7; q < 10; q++) {
        float2 u0 = G[q * 4], u1 = G[q * 4 + 1], u2 = G[q * 4 + 2], u3 = G[q * 4 + 3];
        const int hb = 1 << (9 - q);  // 4,2,1
#pragma unroll
        for (int j0 = 0; j0 < 8; j0++) {
            if ((j0 & hb) == 0) {
                int j1 = j0 | hb;
                float2 s0 = v[j0], s1 = v[j1];
                v[j0] = cadd(cmul(u0, s0), cmul(u1, s1));
                v[j1] = cadd(cmul(u2, s0), cmul(u3, s1));
            }
        }
    }

    // ---- extraction: out += sum_r [pi(r)&15 == pi(c)&15] Re(M6[pi(c)>>4, pi(r)>>4] w[r,c])
    int af = c;
    af ^= af >> 1; af ^= af >> 2; af ^= af >> 4; af ^= af >> 8;  // pi(c)
    int t = af & 15;
    int a05 = af >> 4;
    // prefix parities of lane: pk = parity(lane >> k)
    int p5 = (lane >> 5) & 1;
    int p4 = p5 ^ ((lane >> 4) & 1);
    int p3 = p4 ^ ((lane >> 3) & 1);
    int p2 = p3 ^ ((lane >> 2) & 1);
    int p1 = p2 ^ ((lane >> 1) & 1);
    int p0 = p1 ^ (lane & 1);
    int t3 = (t >> 3) & 1, t2 = (t >> 2) & 1, t1b = (t >> 1) & 1, t0 = t & 1;
    bool sel = ((h ^ p0) == t3);                                    // delta on pi(r) bit 3
    int jsel = ((t2 ^ t3) << 2) | ((t1b ^ t2) << 1) | (t0 ^ t1b);   // wave-uniform
    float2 vs = v[0];
#pragma unroll
    for (int j = 1; j < 8; j++) if (jsel == j) vs = v[j];  // cndmask chain, stays in regs
    // b05 bits (pi(r) bits 9..4) = h ^ {0, p5, p4, p3, p2, p1}
    float2 m6 = make_float2(1.f, 0.f);
    int ib0 = h, ib1 = h ^ p5, ib2 = h ^ p4, ib3 = h ^ p3, ib4 = h ^ p2, ib5 = h ^ p1;
    m6 = cmul(m6, Msh[0 * 4 + ((a05 >> 5) & 1) * 2 + ib0]);
    m6 = cmul(m6, Msh[1 * 4 + ((a05 >> 4) & 1) * 2 + ib1]);
    m6 = cmul(m6, Msh[2 * 4 + ((a05 >> 3) & 1) * 2 + ib2]);
    m6 = cmul(m6, Msh[3 * 4 + ((a05 >> 2) & 1) * 2 + ib3]);
    m6 = cmul(m6, Msh[4 * 4 + ((a05 >> 1) & 1) * 2 + ib4]);
    m6 = cmul(m6, Msh[5 * 4 + (a05 & 1) * 2 + ib5]);

    float acc = sel ? (m6.x * vs.x - m6.y * vs.y) : 0.f;
#pragma unroll
    for (int off = 32; off > 0; off >>= 1) acc += __shfl_xor(acc, off, 64);
    if (lane == 0) part[w] = acc;
    __syncthreads();
    if (tid == 0) {
        float s = part[0] + part[1] + part[2] + part[3] +
                  part[4] + part[5] + part[6] + part[7];
        atomicAdd(out, s);
    }
}

extern "C" void kernel_launch(void* const* d_in, const int* in_sizes, int n_in,
                              void* d_out, int out_size, void* d_ws, size_t ws_size,
                              hipStream_t stream) {
    const float* x = (const float*)d_in[0];       // 1024*1024 fp32
    const float* weight = (const float*)d_in[1];  // 30 fp32
    float* out = (float*)d_out;                   // 1 fp32

    float2* zt = (float2*)d_ws + 8192;  // zt[c][r], 8 MB, 64 KB offset

    pass1<<<256, 512, 0, stream>>>(x, weight, zt, out);
    pass2<<<256, 512, 0, stream>>>(zt, weight, out);
}